// Round 6
// baseline (192.065 us; speedup 1.0000x reference)
//
#include <hip/hip_runtime.h>
#include <stdint.h>

// TMSA: two-stream multi-head causal self-attention, MI355X/gfx950.
// B=8 D=512 H=8 IMG=32 -> S=1024, DH=64.
// Pipeline:
//   1a. xconvert: f32->bf16 vectorized pack Xcat[8192][1024]
//   1b. wtrans  : LDS-tiled transposes -> WcatT[1536][1024] bf16, WoT[512][512] bf16,
//                 WKT[1024][64] f32
//   2.  gemm<0> : QKV = Xcat @ Wcat. 2-phase prefetch double-buffered LDS,
//                 one barrier/K-step. Epilogue folds WK bias into K, log2(e)/8 into Q.
//   3.  vtrans  : V row-major -> VT [bh][d][s]
//   4.  attn    : causal flash attention, ONE q-tile per wave, swapped QK^T so the
//                 softmax row is lane-local; P stays in registers via cvt_pk_bf16 +
//                 permlane16/32_swap (no P-LDS, no lgkm drain). 4-wave blocks share
//                 K/V LDS staging (global_load_lds + source-side XOR swizzle).
//   5.  gemm<1> : out = H @ Wo (f32 epilogue straight to d_out). Hout aliases Xcat.

typedef __bf16 bf16x8 __attribute__((ext_vector_type(8)));
typedef float  f32x4  __attribute__((ext_vector_type(4)));
typedef unsigned short u16x8 __attribute__((ext_vector_type(8)));

#define DEVI __device__ __forceinline__

DEVI unsigned short f2b(float f) {           // f32 -> bf16, round-nearest-even
  union { float f; unsigned u; } v; v.f = f;
  unsigned u = v.u;
  return (unsigned short)((u + 0x7FFFu + ((u >> 16) & 1u)) >> 16);
}

DEVI unsigned cvt_pk(float lo, float hi) {   // packs 2 f32 -> 2 bf16 (RNE)
  unsigned r;
  asm("v_cvt_pk_bf16_f32 %0, %1, %2" : "=v"(r) : "v"(lo), "v"(hi));
  return r;
}
DEVI void pl32(unsigned &a, unsigned &b) {   // rows: a=[a0 a1 b0 b1], b=[a2 a3 b2 b3]
  asm("v_permlane32_swap_b32 %0, %1" : "+v"(a), "+v"(b));
}
DEVI void pl16(unsigned &a, unsigned &b) {   // rows: a=[a0 b0 a2 b2], b=[a1 b1 a3 b3]
  asm("v_permlane16_swap_b32 %0, %1" : "+v"(a), "+v"(b));
}

// ---------------------------------------------------------------- stage 1a: X pack (vectorized)
__global__ __launch_bounds__(256) void xconvert_kernel(
    const float* __restrict__ xs, const float* __restrict__ xt,
    unsigned short* __restrict__ Xcat)
{
  int gid = blockIdx.x * 256 + threadIdx.x;       // 1048576 threads, 8 elems each
  int m = gid >> 7, c0 = (gid & 127) << 3;
  const float* src = (c0 < 512) ? xs + (size_t)m * 512 + c0
                                : xt + (size_t)m * 512 + (c0 - 512);
  float4 a = *(const float4*)src;
  float4 b = *(const float4*)(src + 4);
  u16x8 o;
  o[0] = f2b(a.x); o[1] = f2b(a.y); o[2] = f2b(a.z); o[3] = f2b(a.w);
  o[4] = f2b(b.x); o[5] = f2b(b.y); o[6] = f2b(b.z); o[7] = f2b(b.w);
  *(u16x8*)&Xcat[(size_t)m * 1024 + c0] = o;
}

// ---------------------------------------------------------------- stage 1b: weight transposes
__global__ __launch_bounds__(256) void wtrans_kernel(
    const float* __restrict__ Wqs, const float* __restrict__ Wks, const float* __restrict__ Wvs,
    const float* __restrict__ Wqt, const float* __restrict__ Wkt, const float* __restrict__ Wvt,
    const float* __restrict__ Wo,  const float* __restrict__ WK,
    unsigned short* __restrict__ WcatT, unsigned short* __restrict__ WoT,
    float* __restrict__ WKT)
{
  __shared__ __align__(16) char lds_raw[64 * 65 * 4];
  const int t = threadIdx.x;
  const int r = t >> 2, cb = (t & 3) << 4;
  const int mat = blockIdx.z;

  if (mat < 6) {
    const float* W = (mat == 0) ? Wqs : (mat == 1) ? Wqt : (mat == 2) ? Wks
                   : (mat == 3) ? Wkt : (mat == 4) ? Wvs : Wvt;
    const int ktile = blockIdx.x, ctile = blockIdx.y;
    unsigned short (*tile)[66] = (unsigned short (*)[66])lds_raw;
    const float* src = W + (size_t)(ktile * 64 + r) * 512 + ctile * 64 + cb;
#pragma unroll
    for (int i = 0; i < 4; i++) {
      float4 v = *(const float4*)(src + i * 4);
      tile[r][cb + i * 4 + 0] = f2b(v.x); tile[r][cb + i * 4 + 1] = f2b(v.y);
      tile[r][cb + i * 4 + 2] = f2b(v.z); tile[r][cb + i * 4 + 3] = f2b(v.w);
    }
    __syncthreads();
    const int n = ctile * 64 + r;
    const int sec = mat >> 1, half = mat & 1;
    u16x8 o0, o1;
#pragma unroll
    for (int i = 0; i < 8; i++) { o0[i] = tile[cb + i][r]; o1[i] = tile[cb + 8 + i][r]; }
    unsigned short* dst = WcatT + (size_t)(sec * 512 + n) * 1024 + half * 512 + ktile * 64 + cb;
    *(u16x8*)dst = o0; *(u16x8*)(dst + 8) = o1;
  } else if (mat == 6) {
    const int ktile = blockIdx.x, ctile = blockIdx.y;
    unsigned short (*tile)[66] = (unsigned short (*)[66])lds_raw;
    const float* src = Wo + (size_t)(ktile * 64 + r) * 512 + ctile * 64 + cb;
#pragma unroll
    for (int i = 0; i < 4; i++) {
      float4 v = *(const float4*)(src + i * 4);
      tile[r][cb + i * 4 + 0] = f2b(v.x); tile[r][cb + i * 4 + 1] = f2b(v.y);
      tile[r][cb + i * 4 + 2] = f2b(v.z); tile[r][cb + i * 4 + 3] = f2b(v.w);
    }
    __syncthreads();
    const int n = ctile * 64 + r;
    u16x8 o0, o1;
#pragma unroll
    for (int i = 0; i < 8; i++) { o0[i] = tile[cb + i][r]; o1[i] = tile[cb + 8 + i][r]; }
    unsigned short* dst = WoT + (size_t)n * 512 + ktile * 64 + cb;
    *(u16x8*)dst = o0; *(u16x8*)(dst + 8) = o1;
  } else {
    const int st = blockIdx.y * 8 + blockIdx.x;
    if (st >= 16) return;
    float (*tf)[65] = (float (*)[65])lds_raw;
    const float* src = WK + (size_t)r * 1024 + st * 64 + cb;
#pragma unroll
    for (int i = 0; i < 4; i++) {
      float4 v = *(const float4*)(src + i * 4);
      tf[r][cb + i * 4 + 0] = v.x; tf[r][cb + i * 4 + 1] = v.y;
      tf[r][cb + i * 4 + 2] = v.z; tf[r][cb + i * 4 + 3] = v.w;
    }
    __syncthreads();
    const int s = st * 64 + r;
    float* dst = WKT + (size_t)s * 64 + cb;
#pragma unroll
    for (int i = 0; i < 4; i++) {
      float4 v;
      v.x = tf[cb + i * 4 + 0][r]; v.y = tf[cb + i * 4 + 1][r];
      v.z = tf[cb + i * 4 + 2][r]; v.w = tf[cb + i * 4 + 3][r];
      *(float4*)(dst + i * 4) = v;
    }
  }
}

// ---------------------------------------------------------------- GEMM (A row-major [M,K], BT row-major [N,K])
template <int EPI>
__global__ __launch_bounds__(256) void gemm_bt(
    const unsigned short* __restrict__ A, const unsigned short* __restrict__ BT, int K,
    float* __restrict__ Out, const float* __restrict__ WKT,
    unsigned short* __restrict__ Qb, unsigned short* __restrict__ Kb,
    unsigned short* __restrict__ Vb)
{
  __shared__ unsigned short As[2][128 * 32];
  __shared__ unsigned short Bs[2][128 * 32];
  const int t = threadIdx.x;
  const int lane = t & 63, wid = t >> 6;
  const int wr = wid >> 1, wc = wid & 1;
  const int mtile = blockIdx.x, ntile = blockIdx.y;
  const int arow = t >> 2, acol = (t & 3) << 3;
  const int li = lane & 15, g = lane >> 4;

  f32x4 acc[4][4];
#pragma unroll
  for (int i = 0; i < 4; i++)
#pragma unroll
    for (int j = 0; j < 4; j++) acc[i][j] = (f32x4){0.f, 0.f, 0.f, 0.f};

  const unsigned short* aBase = A + (size_t)(mtile * 128 + arow) * K + acol;
  const unsigned short* bBase = BT + (size_t)(ntile * 128 + arow) * K + acol;

  auto STAGE = [&](int k0, int bf) {
    __builtin_amdgcn_global_load_lds(
        (const __attribute__((address_space(1))) void*)(aBase + k0),
        (__attribute__((address_space(3))) void*)&As[bf][wid * 512], 16, 0, 0);
    __builtin_amdgcn_global_load_lds(
        (const __attribute__((address_space(1))) void*)(aBase + (size_t)64 * K + k0),
        (__attribute__((address_space(3))) void*)&As[bf][2048 + wid * 512], 16, 0, 0);
    __builtin_amdgcn_global_load_lds(
        (const __attribute__((address_space(1))) void*)(bBase + k0),
        (__attribute__((address_space(3))) void*)&Bs[bf][wid * 512], 16, 0, 0);
    __builtin_amdgcn_global_load_lds(
        (const __attribute__((address_space(1))) void*)(bBase + (size_t)64 * K + k0),
        (__attribute__((address_space(3))) void*)&Bs[bf][2048 + wid * 512], 16, 0, 0);
  };

  STAGE(0, 0);
  __syncthreads();

  int cur = 0;
  for (int k0 = 0; k0 < K; k0 += 32) {
    if (k0 + 32 < K) STAGE(k0 + 32, cur ^ 1);   // in flight under this step's MFMAs

    bf16x8 af[4], bfr[4];
#pragma unroll
    for (int fi = 0; fi < 4; fi++)
      af[fi] = *(const bf16x8*)&As[cur][(wr * 64 + fi * 16 + li) * 32 + (g << 3)];
#pragma unroll
    for (int fj = 0; fj < 4; fj++)
      bfr[fj] = *(const bf16x8*)&Bs[cur][(wc * 64 + fj * 16 + li) * 32 + (g << 3)];
    __builtin_amdgcn_s_setprio(1);
#pragma unroll
    for (int fi = 0; fi < 4; fi++)
#pragma unroll
      for (int fj = 0; fj < 4; fj++)
        acc[fi][fj] = __builtin_amdgcn_mfma_f32_16x16x32_bf16(af[fi], bfr[fj], acc[fi][fj], 0, 0, 0);
    __builtin_amdgcn_s_setprio(0);
    __syncthreads();
    cur ^= 1;
  }

  const int lm = g << 2;
  if constexpr (EPI == 0) {
    const float QSCALE = 0.18033688011112042f;  // log2(e)/8 folded into Q
    const int sec = ntile >> 2;                 // block-uniform: 128-tile within one 512-section
#pragma unroll
    for (int fi = 0; fi < 4; fi++) {
      int mg = mtile * 128 + wr * 64 + fi * 16 + lm;
#pragma unroll
      for (int r = 0; r < 4; r++) {
        int m = mg + r;
        int b = m >> 10, s = m & 1023;
        size_t rowo = ((size_t)b * 8) << 16;
        if (sec == 0) {
#pragma unroll
          for (int fj = 0; fj < 4; fj++) {
            int nn = (ntile & 3) * 128 + wc * 64 + fj * 16 + li;
            ((__bf16*)Qb)[rowo + ((size_t)(nn >> 6) << 16) + (size_t)s * 64 + (nn & 63)] =
                (__bf16)(acc[fi][fj][r] * QSCALE);
          }
        } else if (sec == 1) {
#pragma unroll
          for (int fj = 0; fj < 4; fj++) {
            int nn = (ntile & 3) * 128 + wc * 64 + fj * 16 + li;
            int d = nn & 63;
            ((__bf16*)Kb)[rowo + ((size_t)(nn >> 6) << 16) + (size_t)s * 64 + d] =
                (__bf16)(acc[fi][fj][r] + WKT[(size_t)s * 64 + d]);
          }
        } else {
#pragma unroll
          for (int fj = 0; fj < 4; fj++) {
            int nn = (ntile & 3) * 128 + wc * 64 + fj * 16 + li;
            ((__bf16*)Vb)[rowo + ((size_t)(nn >> 6) << 16) + (size_t)s * 64 + (nn & 63)] =
                (__bf16)acc[fi][fj][r];
          }
        }
      }
    }
  } else {
#pragma unroll
    for (int fi = 0; fi < 4; fi++) {
      int mg = mtile * 128 + wr * 64 + fi * 16 + lm;
#pragma unroll
      for (int r = 0; r < 4; r++) {
        size_t m = (size_t)(mg + r);
#pragma unroll
        for (int fj = 0; fj < 4; fj++) {
          int n = ntile * 128 + wc * 64 + fj * 16 + li;
          Out[m * 512 + n] = acc[fi][fj][r];
        }
      }
    }
  }
}

// ---------------------------------------------------------------- stage 3: V [bh][s][d] -> VT [bh][d][s]
__global__ __launch_bounds__(256) void vtrans_kernel(const unsigned short* __restrict__ Vrm,
                                                     unsigned short* __restrict__ VT)
{
  __shared__ unsigned short tile[64][65];
  const int bh = blockIdx.y, st = blockIdx.x;
  const unsigned short* src = Vrm + (size_t)bh * 65536 + (size_t)st * 64 * 64;
#pragma unroll
  for (int i = 0; i < 16; i++) {
    int idx = i * 256 + threadIdx.x;
    tile[idx >> 6][idx & 63] = src[idx];
  }
  __syncthreads();
  unsigned short* dst = VT + (size_t)bh * 65536 + st * 64;
#pragma unroll
  for (int i = 0; i < 16; i++) {
    int idx = i * 256 + threadIdx.x;
    int dl = idx >> 6, s = idx & 63;
    dst[(size_t)dl * 1024 + s] = tile[s][dl];
  }
}

// ---------------------------------------------------------------- stage 4: causal flash attention
// Block = 4 waves; wave w owns ONE 16-row q-tile tl = bx*4+w (bx = 15-blockIdx.x:
// heavy blocks dispatch first). All 4 tiles of a block share nchunk = bx+1 ->
// uniform barriers. K/V staged in LDS (global_load_lds + source-side XOR swizzle).
//
// Swapped QK^T: sc[tt] = mfma(K_frag, Q_frag) -> lane (g,li) reg r holds
// S[q=li][kv = 16tt + 4g + r]: softmax row stats are lane-local (register tree +
// shfl_xor 16/32). P -> bf16 via v_cvt_pk_bf16_f32, redistributed to the PV
// A-fragment with permlane32_swap + permlane16_swap. PV output lane (g,li) reg r
// = H[q=4g+r][d=fj*16+li]; per-q scalars cross over via __shfl(x, 20g+r).
__global__ __launch_bounds__(256) void attn_kernel(
    const unsigned short* __restrict__ Q, const unsigned short* __restrict__ Kp,
    const unsigned short* __restrict__ VT, unsigned short* __restrict__ Hout)
{
  __shared__ unsigned short Ksm[2][4096];   // [buf][row*64 + swizzled 8-elem slots]
  __shared__ unsigned short Vsm[2][4096];

  const int tid = threadIdx.x;
  const int lane = tid & 63, w = tid >> 6;
  const int bx = 15 - (int)blockIdx.x;      // 0..15, heavy first
  const int bh = blockIdx.y;
  const int b = bh >> 3, h = bh & 7;
  const int tl = bx * 4 + w;                // q-tile 0..63
  const int qbase = tl * 16;
  const int nchunk = bx + 1;
  const int g = lane >> 4, li = lane & 15;

  const unsigned short* Kbh = Kp + (size_t)bh * 65536;
  const unsigned short* Vbh = VT + (size_t)bh * 65536;

  auto STAGE = [&](int c, int bf) {
    int j0 = tid, j1 = tid + 256;
    int r0 = j0 >> 3, s0 = (j0 & 7) ^ (r0 & 7);
    int r1 = j1 >> 3, s1 = (j1 & 7) ^ (r1 & 7);
    __builtin_amdgcn_global_load_lds(
        (const __attribute__((address_space(1))) void*)(Kbh + (size_t)(c * 64 + r0) * 64 + s0 * 8),
        (__attribute__((address_space(3))) void*)&Ksm[bf][w * 512], 16, 0, 0);
    __builtin_amdgcn_global_load_lds(
        (const __attribute__((address_space(1))) void*)(Kbh + (size_t)(c * 64 + r1) * 64 + s1 * 8),
        (__attribute__((address_space(3))) void*)&Ksm[bf][2048 + w * 512], 16, 0, 0);
    __builtin_amdgcn_global_load_lds(
        (const __attribute__((address_space(1))) void*)(Vbh + (size_t)r0 * 1024 + c * 64 + s0 * 8),
        (__attribute__((address_space(3))) void*)&Vsm[bf][w * 512], 16, 0, 0);
    __builtin_amdgcn_global_load_lds(
        (const __attribute__((address_space(1))) void*)(Vbh + (size_t)r1 * 1024 + c * 64 + s1 * 8),
        (__attribute__((address_space(3))) void*)&Vsm[bf][2048 + w * 512], 16, 0, 0);
  };

  const unsigned short* Qrow = Q + ((size_t)bh * 1024 + qbase) * 64;
  bf16x8 aq0 = *(const bf16x8*)&Qrow[li * 64 + (g << 3)];
  bf16x8 aq1 = *(const bf16x8*)&Qrow[li * 64 + 32 + (g << 3)];

  f32x4 hacc[4];
#pragma unroll
  for (int fj = 0; fj < 4; fj++) hacc[fj] = (f32x4){0.f, 0.f, 0.f, 0.f};
  float mrow = -3.0e38f, lrow = 0.f;

  STAGE(0, 0);
  __syncthreads();

  for (int c = 0; c < nchunk; c++) {
    const int cur = c & 1;
    if (c + 1 < nchunk) STAGE(c + 1, cur ^ 1);

    bf16x8 bk[4][2];
#pragma unroll
    for (int tt = 0; tt < 4; tt++) {
      int s = tt * 16 + li;
#pragma unroll
      for (int x2 = 0; x2 < 2; x2++)
        bk[tt][x2] = *(const bf16x8*)&Ksm[cur][s * 64 + (((g + 4 * x2) ^ (s & 7)) << 3)];
    }

    // swapped QK^T
    f32x4 sc[4];
    __builtin_amdgcn_s_setprio(1);
#pragma unroll
    for (int tt = 0; tt < 4; tt++) {
      f32x4 z = (f32x4){0.f, 0.f, 0.f, 0.f};
      z = __builtin_amdgcn_mfma_f32_16x16x32_bf16(bk[tt][0], aq0, z, 0, 0, 0);
      z = __builtin_amdgcn_mfma_f32_16x16x32_bf16(bk[tt][1], aq1, z, 0, 0, 0);
      sc[tt] = z;
    }
    __builtin_amdgcn_s_setprio(0);

    if (c == nchunk - 1) {                   // causal mask on the diagonal chunk
      const int kb = c * 64 + 4 * g;
      const int qq = qbase + li;
#pragma unroll
      for (int tt = 0; tt < 4; tt++)
#pragma unroll
        for (int r = 0; r < 4; r++)
          sc[tt][r] = (kb + tt * 16 + r <= qq) ? sc[tt][r] : -3.0e38f;
    }

    // row max: in-lane tree + 2-stage butterfly across g-groups
    float rmA = fmaxf(fmaxf(sc[0][0], sc[0][1]), fmaxf(sc[0][2], sc[0][3]));
    float rmB = fmaxf(fmaxf(sc[1][0], sc[1][1]), fmaxf(sc[1][2], sc[1][3]));
    float rmC = fmaxf(fmaxf(sc[2][0], sc[2][1]), fmaxf(sc[2][2], sc[2][3]));
    float rmD = fmaxf(fmaxf(sc[3][0], sc[3][1]), fmaxf(sc[3][2], sc[3][3]));
    float rm = fmaxf(fmaxf(rmA, rmB), fmaxf(rmC, rmD));
    rm = fmaxf(rm, __shfl_xor(rm, 16, 64));
    rm = fmaxf(rm, __shfl_xor(rm, 32, 64));

    if (!__all(rm <= mrow + 8.0f)) {         // defer-max (exp2 domain, headroom 256x)
      float mn = fmaxf(mrow, rm);
      float scl = exp2f(mrow - mn);
      mrow = mn;
      lrow *= scl;
      float s0 = __shfl(scl, 20 * g + 0, 64);
      float s1 = __shfl(scl, 20 * g + 1, 64);
      float s2 = __shfl(scl, 20 * g + 2, 64);
      float s3 = __shfl(scl, 20 * g + 3, 64);
#pragma unroll
      for (int fj = 0; fj < 4; fj++) {
        hacc[fj][0] *= s0; hacc[fj][1] *= s1; hacc[fj][2] *= s2; hacc[fj][3] *= s3;
      }
    }

#pragma unroll
    for (int tt = 0; tt < 4; tt++)
#pragma unroll
      for (int r = 0; r < 4; r++) sc[tt][r] = exp2f(sc[tt][r] - mrow);
    float psA = (sc[0][0] + sc[0][1]) + (sc[0][2] + sc[0][3]);
    float psB = (sc[1][0] + sc[1][1]) + (sc[1][2] + sc[1][3]);
    float psC = (sc[2][0] + sc[2][1]) + (sc[2][2] + sc[2][3]);
    float psD = (sc[3][0] + sc[3][1]) + (sc[3][2] + sc[3][3]);
    float ps = (psA + psB) + (psC + psD);

    // pack + permlane redistribution into PV A-fragments
    unsigned wpk[4][2];
#pragma unroll
    for (int tt = 0; tt < 4; tt++) {
      wpk[tt][0] = cvt_pk(sc[tt][0], sc[tt][1]);
      wpk[tt][1] = cvt_pk(sc[tt][2], sc[tt][3]);
    }
    unsigned A00 = wpk[0][0], A02 = wpk[1][0]; pl32(A00, A02); pl16(A00, A02);
    unsigned A01 = wpk[0][1], A03 = wpk[1][1]; pl32(A01, A03); pl16(A01, A03);
    unsigned A10 = wpk[2][0], A12 = wpk[3][0]; pl32(A10, A12); pl16(A10, A12);
    unsigned A11 = wpk[2][1], A13 = wpk[3][1]; pl32(A11, A13); pl16(A11, A13);
    union PW { unsigned u[4]; bf16x8 v; } ap0, ap1;
    ap0.u[0] = A00; ap0.u[1] = A01; ap0.u[2] = A02; ap0.u[3] = A03;
    ap1.u[0] = A10; ap1.u[1] = A11; ap1.u[2] = A12; ap1.u[3] = A13;

    bf16x8 bv[4][2];
#pragma unroll
    for (int fj = 0; fj < 4; fj++) {
      int d = fj * 16 + li;
#pragma unroll
      for (int x2 = 0; x2 < 2; x2++)
        bv[fj][x2] = *(const bf16x8*)&Vsm[cur][d * 64 + (((g + 4 * x2) ^ (d & 7)) << 3)];
    }

    __builtin_amdgcn_s_setprio(1);
#pragma unroll
    for (int fj = 0; fj < 4; fj++) {
      hacc[fj] = __builtin_amdgcn_mfma_f32_16x16x32_bf16(ap0.v, bv[fj][0], hacc[fj], 0, 0, 0);
      hacc[fj] = __builtin_amdgcn_mfma_f32_16x16x32_bf16(ap1.v, bv[fj][1], hacc[fj], 0, 0, 0);
    }
    __builtin_amdgcn_s_setprio(0);

    ps += __shfl_xor(ps, 16, 64);
    ps += __shfl_xor(ps, 32, 64);
    lrow += ps;

    __syncthreads();
  }

  float inv = 1.0f / lrow;
  float i0 = __shfl(inv, 20 * g + 0, 64);
  float i1 = __shfl(inv, 20 * g + 1, 64);
  float i2 = __shfl(inv, 20 * g + 2, 64);
  float i3 = __shfl(inv, 20 * g + 3, 64);
#pragma unroll
  for (int fj = 0; fj < 4; fj++) {
    size_t base = ((size_t)b * 1024 + qbase + 4 * g) * 512 + h * 64 + fj * 16 + li;
    Hout[base +   0] = f2b(hacc[fj][0] * i0);
    Hout[base + 512] = f2b(hacc[fj][1] * i1);
    Hout[base + 1024] = f2b(hacc[fj][2] * i2);
    Hout[base + 1536] = f2b(hacc[fj][3] * i3);
  }
}

// ---------------------------------------------------------------- launch
extern "C" void kernel_launch(void* const* d_in, const int* in_sizes, int n_in,
                              void* d_out, int out_size, void* d_ws, size_t ws_size,
                              hipStream_t stream)
{
  const float* xs  = (const float*)d_in[0];
  const float* xt  = (const float*)d_in[1];
  const float* Wqs = (const float*)d_in[2];
  const float* Wks = (const float*)d_in[3];
  const float* Wvs = (const float*)d_in[4];
  const float* Wqt = (const float*)d_in[5];
  const float* Wkt = (const float*)d_in[6];
  const float* Wvt = (const float*)d_in[7];
  const float* WK  = (const float*)d_in[8];
  const float* Wo  = (const float*)d_in[9];
  float* out = (float*)d_out;

  char* ws = (char*)d_ws;
  unsigned short* Xcat  = (unsigned short*)(ws);             // 16,777,216 B
  unsigned short* Hout  = (unsigned short*)(ws);             // aliases Xcat (dead after gemm<0>)
  unsigned short* WcatT = (unsigned short*)(ws + 16777216);  //  3,145,728 B
  unsigned short* WoT   = (unsigned short*)(ws + 19922944);  //    524,288 B
  float*          WKT   = (float*)         (ws + 20447232);  //    262,144 B
  unsigned short* Qb    = (unsigned short*)(ws + 20709376);  //  8,388,608 B
  unsigned short* Kb    = (unsigned short*)(ws + 29097984);  //  8,388,608 B
  unsigned short* Vrm   = (unsigned short*)(ws + 37486592);  //  8,388,608 B
  unsigned short* VT    = (unsigned short*)(ws + 45875200);  //  8,388,608 B  (total 54,263,808)

  xconvert_kernel<<<4096, 256, 0, stream>>>(xs, xt, Xcat);
  wtrans_kernel<<<dim3(8, 8, 8), 256, 0, stream>>>(Wqs, Wks, Wvs, Wqt, Wkt, Wvt, Wo, WK,
                                                   WcatT, WoT, WKT);
  gemm_bt<0><<<dim3(64, 12), 256, 0, stream>>>(Xcat, WcatT, 1024, nullptr, WKT, Qb, Kb, Vrm);
  vtrans_kernel<<<dim3(16, 64), 256, 0, stream>>>(Vrm, VT);
  attn_kernel<<<dim3(16, 64), 256, 0, stream>>>(Qb, Kb, VT, Hout);
  gemm_bt<1><<<dim3(64, 4), 256, 0, stream>>>(Hout, WoT, 512, out, nullptr, nullptr, nullptr, nullptr);
}

// Round 9
// 175.739 us; speedup vs baseline: 1.0929x; 1.0929x over previous
//
#include <hip/hip_runtime.h>
#include <stdint.h>

// TMSA: two-stream multi-head causal self-attention, MI355X/gfx950.
// B=8 D=512 H=8 IMG=32 -> S=1024, DH=64.
// Pipeline:
//   1a. xconvert: f32->bf16 vectorized pack Xcat[8192][1024]
//   1b. wtrans  : LDS-tiled transposes -> WcatT[1536][1024] bf16, WoT[512][512] bf16,
//                 WKT[1024][64] f32
//   2.  gemm<0> : QKV = Xcat @ Wcat. 2-phase prefetch double-buffered LDS,
//                 one barrier/K-step. Epilogue folds WK bias into K, log2(e)/8 into Q.
//   3.  vtrans  : V row-major -> VT [bh][d][s]
//   4.  attn    : causal flash attention, ONE q-tile per wave, swapped QK^T,
//                 register-P softmax (cvt_pk + permlane swaps for the A-fragment
//                 redistribution only -- reductions stay __shfl_xor, the permlane
//                 butterfly variant FAILED correctness in R8). Grid dim3(64,16):
//                 bid = bh + 64*cls -> same-column blocks share an XCD (L2 reuse);
//                 bx = perm(cls) makes every CU's 4 striped blocks sum to exactly
//                 34 chunk-units (fixes the 16-CU heavy-block pileup of R2/R6).
//   5.  gemm<1> : out = H @ Wo (f32 epilogue straight to d_out). Hout aliases Xcat.

typedef __bf16 bf16x8 __attribute__((ext_vector_type(8)));
typedef float  f32x4  __attribute__((ext_vector_type(4)));
typedef unsigned short u16x8 __attribute__((ext_vector_type(8)));

#define DEVI __device__ __forceinline__

DEVI unsigned short f2b(float f) {           // f32 -> bf16, round-nearest-even
  union { float f; unsigned u; } v; v.f = f;
  unsigned u = v.u;
  return (unsigned short)((u + 0x7FFFu + ((u >> 16) & 1u)) >> 16);
}

DEVI unsigned cvt_pk(float lo, float hi) {   // packs 2 f32 -> 2 bf16 (RNE)
  unsigned r;
  asm("v_cvt_pk_bf16_f32 %0, %1, %2" : "=v"(r) : "v"(lo), "v"(hi));
  return r;
}
DEVI void pl32(unsigned &a, unsigned &b) {   // rows: a=[a0 a1 b0 b1], b=[a2 a3 b2 b3]
  asm("v_permlane32_swap_b32 %0, %1" : "+v"(a), "+v"(b));
}
DEVI void pl16(unsigned &a, unsigned &b) {   // rows: a=[a0 b0 a2 b2], b=[a1 b1 a3 b3]
  asm("v_permlane16_swap_b32 %0, %1" : "+v"(a), "+v"(b));
}

// ---------------------------------------------------------------- stage 1a: X pack (vectorized)
__global__ __launch_bounds__(256) void xconvert_kernel(
    const float* __restrict__ xs, const float* __restrict__ xt,
    unsigned short* __restrict__ Xcat)
{
  int gid = blockIdx.x * 256 + threadIdx.x;       // 1048576 threads, 8 elems each
  int m = gid >> 7, c0 = (gid & 127) << 3;
  const float* src = (c0 < 512) ? xs + (size_t)m * 512 + c0
                                : xt + (size_t)m * 512 + (c0 - 512);
  float4 a = *(const float4*)src;
  float4 b = *(const float4*)(src + 4);
  u16x8 o;
  o[0] = f2b(a.x); o[1] = f2b(a.y); o[2] = f2b(a.z); o[3] = f2b(a.w);
  o[4] = f2b(b.x); o[5] = f2b(b.y); o[6] = f2b(b.z); o[7] = f2b(b.w);
  *(u16x8*)&Xcat[(size_t)m * 1024 + c0] = o;
}

// ---------------------------------------------------------------- stage 1b: weight transposes
__global__ __launch_bounds__(256) void wtrans_kernel(
    const float* __restrict__ Wqs, const float* __restrict__ Wks, const float* __restrict__ Wvs,
    const float* __restrict__ Wqt, const float* __restrict__ Wkt, const float* __restrict__ Wvt,
    const float* __restrict__ Wo,  const float* __restrict__ WK,
    unsigned short* __restrict__ WcatT, unsigned short* __restrict__ WoT,
    float* __restrict__ WKT)
{
  __shared__ __align__(16) char lds_raw[64 * 65 * 4];
  const int t = threadIdx.x;
  const int r = t >> 2, cb = (t & 3) << 4;
  const int mat = blockIdx.z;

  if (mat < 6) {
    const float* W = (mat == 0) ? Wqs : (mat == 1) ? Wqt : (mat == 2) ? Wks
                   : (mat == 3) ? Wkt : (mat == 4) ? Wvs : Wvt;
    const int ktile = blockIdx.x, ctile = blockIdx.y;
    unsigned short (*tile)[66] = (unsigned short (*)[66])lds_raw;
    const float* src = W + (size_t)(ktile * 64 + r) * 512 + ctile * 64 + cb;
#pragma unroll
    for (int i = 0; i < 4; i++) {
      float4 v = *(const float4*)(src + i * 4);
      tile[r][cb + i * 4 + 0] = f2b(v.x); tile[r][cb + i * 4 + 1] = f2b(v.y);
      tile[r][cb + i * 4 + 2] = f2b(v.z); tile[r][cb + i * 4 + 3] = f2b(v.w);
    }
    __syncthreads();
    const int n = ctile * 64 + r;
    const int sec = mat >> 1, half = mat & 1;
    u16x8 o0, o1;
#pragma unroll
    for (int i = 0; i < 8; i++) { o0[i] = tile[cb + i][r]; o1[i] = tile[cb + 8 + i][r]; }
    unsigned short* dst = WcatT + (size_t)(sec * 512 + n) * 1024 + half * 512 + ktile * 64 + cb;
    *(u16x8*)dst = o0; *(u16x8*)(dst + 8) = o1;
  } else if (mat == 6) {
    const int ktile = blockIdx.x, ctile = blockIdx.y;
    unsigned short (*tile)[66] = (unsigned short (*)[66])lds_raw;
    const float* src = Wo + (size_t)(ktile * 64 + r) * 512 + ctile * 64 + cb;
#pragma unroll
    for (int i = 0; i < 4; i++) {
      float4 v = *(const float4*)(src + i * 4);
      tile[r][cb + i * 4 + 0] = f2b(v.x); tile[r][cb + i * 4 + 1] = f2b(v.y);
      tile[r][cb + i * 4 + 2] = f2b(v.z); tile[r][cb + i * 4 + 3] = f2b(v.w);
    }
    __syncthreads();
    const int n = ctile * 64 + r;
    u16x8 o0, o1;
#pragma unroll
    for (int i = 0; i < 8; i++) { o0[i] = tile[cb + i][r]; o1[i] = tile[cb + 8 + i][r]; }
    unsigned short* dst = WoT + (size_t)n * 512 + ktile * 64 + cb;
    *(u16x8*)dst = o0; *(u16x8*)(dst + 8) = o1;
  } else {
    const int st = blockIdx.y * 8 + blockIdx.x;
    if (st >= 16) return;
    float (*tf)[65] = (float (*)[65])lds_raw;
    const float* src = WK + (size_t)r * 1024 + st * 64 + cb;
#pragma unroll
    for (int i = 0; i < 4; i++) {
      float4 v = *(const float4*)(src + i * 4);
      tf[r][cb + i * 4 + 0] = v.x; tf[r][cb + i * 4 + 1] = v.y;
      tf[r][cb + i * 4 + 2] = v.z; tf[r][cb + i * 4 + 3] = v.w;
    }
    __syncthreads();
    const int s = st * 64 + r;
    float* dst = WKT + (size_t)s * 64 + cb;
#pragma unroll
    for (int i = 0; i < 4; i++) {
      float4 v;
      v.x = tf[cb + i * 4 + 0][r]; v.y = tf[cb + i * 4 + 1][r];
      v.z = tf[cb + i * 4 + 2][r]; v.w = tf[cb + i * 4 + 3][r];
      *(float4*)(dst + i * 4) = v;
    }
  }
}

// ---------------------------------------------------------------- GEMM (A row-major [M,K], BT row-major [N,K])
template <int EPI>
__global__ __launch_bounds__(256) void gemm_bt(
    const unsigned short* __restrict__ A, const unsigned short* __restrict__ BT, int K,
    float* __restrict__ Out, const float* __restrict__ WKT,
    unsigned short* __restrict__ Qb, unsigned short* __restrict__ Kb,
    unsigned short* __restrict__ Vb)
{
  __shared__ unsigned short As[2][128 * 32];
  __shared__ unsigned short Bs[2][128 * 32];
  const int t = threadIdx.x;
  const int lane = t & 63, wid = t >> 6;
  const int wr = wid >> 1, wc = wid & 1;
  const int mtile = blockIdx.x, ntile = blockIdx.y;
  const int arow = t >> 2, acol = (t & 3) << 3;
  const int li = lane & 15, g = lane >> 4;

  f32x4 acc[4][4];
#pragma unroll
  for (int i = 0; i < 4; i++)
#pragma unroll
    for (int j = 0; j < 4; j++) acc[i][j] = (f32x4){0.f, 0.f, 0.f, 0.f};

  const unsigned short* aBase = A + (size_t)(mtile * 128 + arow) * K + acol;
  const unsigned short* bBase = BT + (size_t)(ntile * 128 + arow) * K + acol;

  auto STAGE = [&](int k0, int bf) {
    __builtin_amdgcn_global_load_lds(
        (const __attribute__((address_space(1))) void*)(aBase + k0),
        (__attribute__((address_space(3))) void*)&As[bf][wid * 512], 16, 0, 0);
    __builtin_amdgcn_global_load_lds(
        (const __attribute__((address_space(1))) void*)(aBase + (size_t)64 * K + k0),
        (__attribute__((address_space(3))) void*)&As[bf][2048 + wid * 512], 16, 0, 0);
    __builtin_amdgcn_global_load_lds(
        (const __attribute__((address_space(1))) void*)(bBase + k0),
        (__attribute__((address_space(3))) void*)&Bs[bf][wid * 512], 16, 0, 0);
    __builtin_amdgcn_global_load_lds(
        (const __attribute__((address_space(1))) void*)(bBase + (size_t)64 * K + k0),
        (__attribute__((address_space(3))) void*)&Bs[bf][2048 + wid * 512], 16, 0, 0);
  };

  STAGE(0, 0);
  __syncthreads();

  int cur = 0;
  for (int k0 = 0; k0 < K; k0 += 32) {
    if (k0 + 32 < K) STAGE(k0 + 32, cur ^ 1);   // in flight under this step's MFMAs

    bf16x8 af[4], bfr[4];
#pragma unroll
    for (int fi = 0; fi < 4; fi++)
      af[fi] = *(const bf16x8*)&As[cur][(wr * 64 + fi * 16 + li) * 32 + (g << 3)];
#pragma unroll
    for (int fj = 0; fj < 4; fj++)
      bfr[fj] = *(const bf16x8*)&Bs[cur][(wc * 64 + fj * 16 + li) * 32 + (g << 3)];
    __builtin_amdgcn_s_setprio(1);
#pragma unroll
    for (int fi = 0; fi < 4; fi++)
#pragma unroll
      for (int fj = 0; fj < 4; fj++)
        acc[fi][fj] = __builtin_amdgcn_mfma_f32_16x16x32_bf16(af[fi], bfr[fj], acc[fi][fj], 0, 0, 0);
    __builtin_amdgcn_s_setprio(0);
    __syncthreads();
    cur ^= 1;
  }

  const int lm = g << 2;
  if constexpr (EPI == 0) {
    const float QSCALE = 0.18033688011112042f;  // log2(e)/8 folded into Q
    const int sec = ntile >> 2;                 // block-uniform: 128-tile within one 512-section
#pragma unroll
    for (int fi = 0; fi < 4; fi++) {
      int mg = mtile * 128 + wr * 64 + fi * 16 + lm;
#pragma unroll
      for (int r = 0; r < 4; r++) {
        int m = mg + r;
        int b = m >> 10, s = m & 1023;
        size_t rowo = ((size_t)b * 8) << 16;
        if (sec == 0) {
#pragma unroll
          for (int fj = 0; fj < 4; fj++) {
            int nn = (ntile & 3) * 128 + wc * 64 + fj * 16 + li;
            ((__bf16*)Qb)[rowo + ((size_t)(nn >> 6) << 16) + (size_t)s * 64 + (nn & 63)] =
                (__bf16)(acc[fi][fj][r] * QSCALE);
          }
        } else if (sec == 1) {
#pragma unroll
          for (int fj = 0; fj < 4; fj++) {
            int nn = (ntile & 3) * 128 + wc * 64 + fj * 16 + li;
            int d = nn & 63;
            ((__bf16*)Kb)[rowo + ((size_t)(nn >> 6) << 16) + (size_t)s * 64 + d] =
                (__bf16)(acc[fi][fj][r] + WKT[(size_t)s * 64 + d]);
          }
        } else {
#pragma unroll
          for (int fj = 0; fj < 4; fj++) {
            int nn = (ntile & 3) * 128 + wc * 64 + fj * 16 + li;
            ((__bf16*)Vb)[rowo + ((size_t)(nn >> 6) << 16) + (size_t)s * 64 + (nn & 63)] =
                (__bf16)acc[fi][fj][r];
          }
        }
      }
    }
  } else {
#pragma unroll
    for (int fi = 0; fi < 4; fi++) {
      int mg = mtile * 128 + wr * 64 + fi * 16 + lm;
#pragma unroll
      for (int r = 0; r < 4; r++) {
        size_t m = (size_t)(mg + r);
#pragma unroll
        for (int fj = 0; fj < 4; fj++) {
          int n = ntile * 128 + wc * 64 + fj * 16 + li;
          Out[m * 512 + n] = acc[fi][fj][r];
        }
      }
    }
  }
}

// ---------------------------------------------------------------- stage 3: V [bh][s][d] -> VT [bh][d][s]
__global__ __launch_bounds__(256) void vtrans_kernel(const unsigned short* __restrict__ Vrm,
                                                     unsigned short* __restrict__ VT)
{
  __shared__ unsigned short tile[64][65];
  const int bh = blockIdx.y, st = blockIdx.x;
  const unsigned short* src = Vrm + (size_t)bh * 65536 + (size_t)st * 64 * 64;
#pragma unroll
  for (int i = 0; i < 16; i++) {
    int idx = i * 256 + threadIdx.x;
    tile[idx >> 6][idx & 63] = src[idx];
  }
  __syncthreads();
  unsigned short* dst = VT + (size_t)bh * 65536 + st * 64;
#pragma unroll
  for (int i = 0; i < 16; i++) {
    int idx = i * 256 + threadIdx.x;
    int dl = idx >> 6, s = idx & 63;
    dst[(size_t)dl * 1024 + s] = tile[s][dl];
  }
}

// ---------------------------------------------------------------- stage 4: causal flash attention
// Grid dim3(64,16): blockIdx.x = bh (column), blockIdx.y = cls.
//   bid = bh + 64*cls  ->  bid%8 = bh%8: all 16 blocks of a column share an XCD.
//   bx = perm(cls), perm = {15-2k},{14-2k},{2k},{2k+1} for cls = k+4q (bijection
//   on 0..15): under stride-256 bid->CU striping each CU's 4 resident blocks have
//   (bx+1) sums = (16-2k)+(15-2k)+(2k+1)+(2k+2) = 34 chunk-units for EVERY k.
// Block = 4 waves; wave w owns ONE 16-row q-tile tl = bx*4+w; nchunk = bx+1,
// uniform within the block. K/V staged in LDS (global_load_lds + src-side XOR
// swizzle, double-buffered). Swapped QK^T -> lane-local softmax rows; register-P
// via cvt_pk + permlane swaps. Reductions use __shfl_xor (HW-proven; the
// identical-operand permlane butterfly variant failed correctness in R8).
__global__ __launch_bounds__(256) void attn_kernel(
    const unsigned short* __restrict__ Q, const unsigned short* __restrict__ Kp,
    const unsigned short* __restrict__ VT, unsigned short* __restrict__ Hout)
{
  __shared__ unsigned short Ksm[2][4096];   // [buf][row*64 + swizzled 8-elem slots]
  __shared__ unsigned short Vsm[2][4096];

  const int tid = threadIdx.x;
  const int lane = tid & 63, w = tid >> 6;
  const int cls = blockIdx.y;
  const int k4 = cls & 3, q4 = cls >> 2;
  const int bx = (q4 == 0) ? 15 - 2 * k4
               : (q4 == 1) ? 14 - 2 * k4
               : (q4 == 2) ? 2 * k4
                           : 2 * k4 + 1;     // balanced class permutation
  const int bh = blockIdx.x;
  const int b = bh >> 3, h = bh & 7;
  const int tl = bx * 4 + w;                // q-tile 0..63
  const int qbase = tl * 16;
  const int nchunk = bx + 1;
  const int g = lane >> 4, li = lane & 15;

  const unsigned short* Kbh = Kp + (size_t)bh * 65536;
  const unsigned short* Vbh = VT + (size_t)bh * 65536;

  auto STAGE = [&](int c, int bf) {
    int j0 = tid, j1 = tid + 256;
    int r0 = j0 >> 3, s0 = (j0 & 7) ^ (r0 & 7);
    int r1 = j1 >> 3, s1 = (j1 & 7) ^ (r1 & 7);
    __builtin_amdgcn_global_load_lds(
        (const __attribute__((address_space(1))) void*)(Kbh + (size_t)(c * 64 + r0) * 64 + s0 * 8),
        (__attribute__((address_space(3))) void*)&Ksm[bf][w * 512], 16, 0, 0);
    __builtin_amdgcn_global_load_lds(
        (const __attribute__((address_space(1))) void*)(Kbh + (size_t)(c * 64 + r1) * 64 + s1 * 8),
        (__attribute__((address_space(3))) void*)&Ksm[bf][2048 + w * 512], 16, 0, 0);
    __builtin_amdgcn_global_load_lds(
        (const __attribute__((address_space(1))) void*)(Vbh + (size_t)r0 * 1024 + c * 64 + s0 * 8),
        (__attribute__((address_space(3))) void*)&Vsm[bf][w * 512], 16, 0, 0);
    __builtin_amdgcn_global_load_lds(
        (const __attribute__((address_space(1))) void*)(Vbh + (size_t)r1 * 1024 + c * 64 + s1 * 8),
        (__attribute__((address_space(3))) void*)&Vsm[bf][2048 + w * 512], 16, 0, 0);
  };

  const unsigned short* Qrow = Q + ((size_t)bh * 1024 + qbase) * 64;
  bf16x8 aq0 = *(const bf16x8*)&Qrow[li * 64 + (g << 3)];
  bf16x8 aq1 = *(const bf16x8*)&Qrow[li * 64 + 32 + (g << 3)];

  f32x4 hacc[4];
#pragma unroll
  for (int fj = 0; fj < 4; fj++) hacc[fj] = (f32x4){0.f, 0.f, 0.f, 0.f};
  float mrow = -3.0e38f, lrow = 0.f;

  STAGE(0, 0);
  __syncthreads();

  for (int c = 0; c < nchunk; c++) {
    const int cur = c & 1;
    if (c + 1 < nchunk) STAGE(c + 1, cur ^ 1);

    bf16x8 bk[4][2];
#pragma unroll
    for (int tt = 0; tt < 4; tt++) {
      int s = tt * 16 + li;
#pragma unroll
      for (int x2 = 0; x2 < 2; x2++)
        bk[tt][x2] = *(const bf16x8*)&Ksm[cur][s * 64 + (((g + 4 * x2) ^ (s & 7)) << 3)];
    }

    // swapped QK^T: lane (g,li) reg r = S[q=li][kv = 16tt + 4g + r]
    f32x4 sc[4];
    __builtin_amdgcn_s_setprio(1);
#pragma unroll
    for (int tt = 0; tt < 4; tt++) {
      f32x4 z = (f32x4){0.f, 0.f, 0.f, 0.f};
      z = __builtin_amdgcn_mfma_f32_16x16x32_bf16(bk[tt][0], aq0, z, 0, 0, 0);
      z = __builtin_amdgcn_mfma_f32_16x16x32_bf16(bk[tt][1], aq1, z, 0, 0, 0);
      sc[tt] = z;
    }
    __builtin_amdgcn_s_setprio(0);

    if (c == nchunk - 1) {                   // causal mask on the diagonal chunk
      const int kb = c * 64 + 4 * g;
      const int qq = qbase + li;
#pragma unroll
      for (int tt = 0; tt < 4; tt++)
#pragma unroll
        for (int r = 0; r < 4; r++)
          sc[tt][r] = (kb + tt * 16 + r <= qq) ? sc[tt][r] : -3.0e38f;
    }

    // row max: in-lane tree + __shfl_xor across the 4 g-groups (HW-proven path)
    float rmA = fmaxf(fmaxf(sc[0][0], sc[0][1]), fmaxf(sc[0][2], sc[0][3]));
    float rmB = fmaxf(fmaxf(sc[1][0], sc[1][1]), fmaxf(sc[1][2], sc[1][3]));
    float rmC = fmaxf(fmaxf(sc[2][0], sc[2][1]), fmaxf(sc[2][2], sc[2][3]));
    float rmD = fmaxf(fmaxf(sc[3][0], sc[3][1]), fmaxf(sc[3][2], sc[3][3]));
    float rm = fmaxf(fmaxf(rmA, rmB), fmaxf(rmC, rmD));
    rm = fmaxf(rm, __shfl_xor(rm, 16, 64));
    rm = fmaxf(rm, __shfl_xor(rm, 32, 64));

    if (!__all(rm <= mrow + 8.0f)) {         // defer-max (exp2 domain, headroom 256x)
      float mn = fmaxf(mrow, rm);
      float scl = exp2f(mrow - mn);
      mrow = mn;
      lrow *= scl;
      float s0 = __shfl(scl, 20 * g + 0, 64);
      float s1 = __shfl(scl, 20 * g + 1, 64);
      float s2 = __shfl(scl, 20 * g + 2, 64);
      float s3 = __shfl(scl, 20 * g + 3, 64);
#pragma unroll
      for (int fj = 0; fj < 4; fj++) {
        hacc[fj][0] *= s0; hacc[fj][1] *= s1; hacc[fj][2] *= s2; hacc[fj][3] *= s3;
      }
    }

#pragma unroll
    for (int tt = 0; tt < 4; tt++)
#pragma unroll
      for (int r = 0; r < 4; r++) sc[tt][r] = exp2f(sc[tt][r] - mrow);
    float psA = (sc[0][0] + sc[0][1]) + (sc[0][2] + sc[0][3]);
    float psB = (sc[1][0] + sc[1][1]) + (sc[1][2] + sc[1][3]);
    float psC = (sc[2][0] + sc[2][1]) + (sc[2][2] + sc[2][3]);
    float psD = (sc[3][0] + sc[3][1]) + (sc[3][2] + sc[3][3]);
    float ps = (psA + psB) + (psC + psD);

    // pack + permlane redistribution into PV A-fragments (distinct operands: HW-proven)
    unsigned wpk[4][2];
#pragma unroll
    for (int tt = 0; tt < 4; tt++) {
      wpk[tt][0] = cvt_pk(sc[tt][0], sc[tt][1]);
      wpk[tt][1] = cvt_pk(sc[tt][2], sc[tt][3]);
    }
    unsigned A00 = wpk[0][0], A02 = wpk[1][0]; pl32(A00, A02); pl16(A00, A02);
    unsigned A01 = wpk[0][1], A03 = wpk[1][1]; pl32(A01, A03); pl16(A01, A03);
    unsigned A10 = wpk[2][0], A12 = wpk[3][0]; pl32(A10, A12); pl16(A10, A12);
    unsigned A11 = wpk[2][1], A13 = wpk[3][1]; pl32(A11, A13); pl16(A11, A13);
    union PW { unsigned u[4]; bf16x8 v; } ap0, ap1;
    ap0.u[0] = A00; ap0.u[1] = A01; ap0.u[2] = A02; ap0.u[3] = A03;
    ap1.u[0] = A10; ap1.u[1] = A11; ap1.u[2] = A12; ap1.u[3] = A13;

    bf16x8 bv[4][2];
#pragma unroll
    for (int fj = 0; fj < 4; fj++) {
      int d = fj * 16 + li;
#pragma unroll
      for (int x2 = 0; x2 < 2; x2++)
        bv[fj][x2] = *(const bf16x8*)&Vsm[cur][d * 64 + (((g + 4 * x2) ^ (d & 7)) << 3)];
    }

    __builtin_amdgcn_s_setprio(1);
#pragma unroll
    for (int fj = 0; fj < 4; fj++) {
      hacc[fj] = __builtin_amdgcn_mfma_f32_16x16x32_bf16(ap0.v, bv[fj][0], hacc[fj], 0, 0, 0);
      hacc[fj] = __builtin_amdgcn_mfma_f32_16x16x32_bf16(ap1.v, bv[fj][1], hacc[fj], 0, 0, 0);
    }
    __builtin_amdgcn_s_setprio(0);

    ps += __shfl_xor(ps, 16, 64);
    ps += __shfl_xor(ps, 32, 64);
    lrow += ps;

    __syncthreads();
  }

  float inv = 1.0f / lrow;
  float i0 = __shfl(inv, 20 * g + 0, 64);
  float i1 = __shfl(inv, 20 * g + 1, 64);
  float i2 = __shfl(inv, 20 * g + 2, 64);
  float i3 = __shfl(inv, 20 * g + 3, 64);
#pragma unroll
  for (int fj = 0; fj < 4; fj++) {
    size_t base = ((size_t)b * 1024 + qbase + 4 * g) * 512 + h * 64 + fj * 16 + li;
    Hout[base +    0] = f2b(hacc[fj][0] * i0);
    Hout[base +  512] = f2b(hacc[fj][1] * i1);
    Hout[base + 1024] = f2b(hacc[fj][2] * i2);
    Hout[base + 1536] = f2b(hacc[fj][3] * i3);
  }
}

// ---------------------------------------------------------------- launch
extern "C" void kernel_launch(void* const* d_in, const int* in_sizes, int n_in,
                              void* d_out, int out_size, void* d_ws, size_t ws_size,
                              hipStream_t stream)
{
  const float* xs  = (const float*)d_in[0];
  const float* xt  = (const float*)d_in[1];
  const float* Wqs = (const float*)d_in[2];
  const float* Wks = (const float*)d_in[3];
  const float* Wvs = (const float*)d_in[4];
  const float* Wqt = (const float*)d_in[5];
  const float* Wkt = (const float*)d_in[6];
  const float* Wvt = (const float*)d_in[7];
  const float* WK  = (const float*)d_in[8];
  const float* Wo  = (const float*)d_in[9];
  float* out = (float*)d_out;

  char* ws = (char*)d_ws;
  unsigned short* Xcat  = (unsigned short*)(ws);             // 16,777,216 B
  unsigned short* Hout  = (unsigned short*)(ws);             // aliases Xcat (dead after gemm<0>)
  unsigned short* WcatT = (unsigned short*)(ws + 16777216);  //  3,145,728 B
  unsigned short* WoT   = (unsigned short*)(ws + 19922944);  //    524,288 B
  float*          WKT   = (float*)         (ws + 20447232);  //    262,144 B
  unsigned short* Qb    = (unsigned short*)(ws + 20709376);  //  8,388,608 B
  unsigned short* Kb    = (unsigned short*)(ws + 29097984);  //  8,388,608 B
  unsigned short* Vrm   = (unsigned short*)(ws + 37486592);  //  8,388,608 B
  unsigned short* VT    = (unsigned short*)(ws + 45875200);  //  8,388,608 B  (total 54,263,808)

  xconvert_kernel<<<4096, 256, 0, stream>>>(xs, xt, Xcat);
  wtrans_kernel<<<dim3(8, 8, 8), 256, 0, stream>>>(Wqs, Wks, Wvs, Wqt, Wkt, Wvt, Wo, WK,
                                                   WcatT, WoT, WKT);
  gemm_bt<0><<<dim3(64, 12), 256, 0, stream>>>(Xcat, WcatT, 1024, nullptr, WKT, Qb, Kb, Vrm);
  vtrans_kernel<<<dim3(16, 64), 256, 0, stream>>>(Vrm, VT);
  attn_kernel<<<dim3(64, 16), 256, 0, stream>>>(Qb, Kb, VT, Hout);
  gemm_bt<1><<<dim3(64, 4), 256, 0, stream>>>(Hout, WoT, 512, out, nullptr, nullptr, nullptr, nullptr);
}